// Round 8
// baseline (165.400 us; speedup 1.0000x reference)
//
#include <hip/hip_runtime.h>

// KAN-CNN via MFMA: out[b,f,h,w] = sum_{dy,dx,c} R_{f,dy,dx,c}( xpad[b,c,h+dy-1,w+dx-1] )
// R(x) = P5(x)/(1+|x*Q(x)|).
//
// R12 = R11 + hazard-correct raw-asm MFMA (forces D into arch VGPRs).
// Evidence: R11 VGPR_Count=36 -> compiler banks MFMA C/D in AGPRs by
// policy even with a 512-reg budget; per-tap-wave VALU issue 332 cyc vs
// ~180 of math == accvgpr-move tax. R10's NaN: inline-asm MFMA gets no
// compiler wait states (hazard recognizer can't see asm bodies). Fix:
// one asm block = s_nop 1 lead (VALU-write->MFMA-src hazard), den-MFMA
// then num-MFMA, 3x s_nop 7 (24 cyc >= ~18 req'd for 16-pass MFMA ->
// VALU read of D). "=&v" outputs keep D in VGPRs; no accvgpr traffic.
// Also: strength-reduced prefetch addressing (elem += PPLANE, full
// recompute only at wave-uniform k2 boundaries) and 32KB XOR-swizzled
// LDS reduction (2-way conflict = free; may lift 49% occupancy if the
// 34.8KB alloc was rounding to a coarser granule).
//
// Precision unchanged from R8: hi/lo split on coeffs AND powers, K=16
// filled; C/D map m74/m101: row=(r&3)+8*(r>>2)+4*(lane>>5), col=lane&31.

typedef int   iv4  __attribute__((ext_vector_type(4)));
typedef short s8v  __attribute__((ext_vector_type(8)));
typedef float f16v __attribute__((ext_vector_type(16)));

#define Bb 8
#define Cc 32
#define Hh 64
#define Ww 64
#define Ff 64
#define PW 66
#define PPLANE (PW * PW)             // 4356
#define NELEM  (Bb * Cc * PPLANE)    // 1,115,136 elements
#define NTAP   288
#define PWBLK  (NELEM / 256)         // 4356 blocks for powers part

static __device__ __forceinline__ unsigned short f2bf(float f) {
    unsigned u = __builtin_bit_cast(unsigned, f);
    u += 0x7fffu + ((u >> 16) & 1u);           // RNE
    return (unsigned short)(u >> 16);
}
static __device__ __forceinline__ float bf2f(unsigned short h) {
    unsigned u = ((unsigned)h) << 16;
    return __builtin_bit_cast(float, u);
}
static __device__ __forceinline__ int pack2(unsigned short a, unsigned short b) {
    return (int)((unsigned)a | ((unsigned)b << 16));
}

// Two MFMAs with explicit wait states; D forced into arch VGPRs.
// Dd issued first so its D is read first in the epilogue (max slack).
static __device__ __forceinline__ void mfma2_v(s8v ad, s8v an, s8v b, f16v zf,
                                               f16v& Dd, f16v& Dn) {
    asm("s_nop 1\n\t"
        "v_mfma_f32_32x32x16_bf16 %0, %2, %4, %5\n\t"
        "v_mfma_f32_32x32x16_bf16 %1, %3, %4, %5\n\t"
        "s_nop 7\n\t"
        "s_nop 7\n\t"
        "s_nop 7"
        : "=&v"(Dd), "=&v"(Dn)
        : "v"(ad), "v"(an), "v"(b), "v"(zf));
}

// Merged prep: blocks [0, PWBLK) build the powers planes; blocks
// [PWBLK, PWBLK+288) build the A-coefficient fragments.
__global__ __launch_bounds__(256) void prep_kernel(
    const float* __restrict__ x,
    const float* __restrict__ ncf, const float* __restrict__ dcf,
    iv4* __restrict__ pw, iv4* __restrict__ ac)
{
    if ((int)blockIdx.x < PWBLK) {
        // ---- powers: two 16B rows per padded element, layout [g][elem] ----
        int idx = (int)blockIdx.x * 256 + (int)threadIdx.x;
        int wp = idx % PW;
        int r1 = idx / PW;
        int hp = r1 % PW;
        int pl = r1 / PW;                                 // b*32+c
        float v = 0.0f;
        if (hp >= 1 && hp <= Hh && wp >= 1 && wp <= Ww)
            v = x[((size_t)pl * Hh + (hp - 1)) * Ww + (wp - 1)];
        float p2 = v * v, p3 = p2 * v, p4 = p2 * p2, p5 = p4 * v;
        float pv[6] = {1.0f, v, p2, p3, p4, p5};
        unsigned short hi[6], lo[6];
#pragma unroll
        for (int e = 0; e < 6; ++e) {
            hi[e] = f2bf(pv[e]);
            lo[e] = f2bf(pv[e] - bf2f(hi[e]));
        }
        iv4 r0, r1v;
        r0.x  = pack2(hi[0], hi[1]); r0.y  = pack2(hi[2], hi[3]);
        r0.z  = pack2(hi[4], hi[5]); r0.w  = pack2(lo[1], lo[2]);
        r1v.x = pack2(lo[3], lo[4]); r1v.y = pack2(lo[5], hi[1]);
        r1v.z = pack2(hi[2], hi[3]); r1v.w = pack2(hi[4], hi[5]);
        pw[idx]         = r0;    // g=0 plane
        pw[NELEM + idx] = r1v;   // g=1 plane
    } else {
        // ---- A fragments: load-order [t(288)][Mtile(4)][lane(64)] x 16B ----
        // tiles: 0=num f0-31, 1=num f32-63, 2=den f0-31, 3=den f32-63
        int idx = ((int)blockIdx.x - PWBLK) * 256 + (int)threadIdx.x;
        int l = idx & 63, tile = (idx >> 6) & 3, t = idx >> 8;
        int m = l & 31, g = l >> 5;
        float cv[6];
        if (tile < 2) {
            int f = tile * 32 + m;
            const float* s = ncf + ((size_t)f * NTAP + t) * 6;
            cv[0] = s[0]; cv[1] = s[1]; cv[2] = s[2];
            cv[3] = s[3]; cv[4] = s[4]; cv[5] = s[5];
        } else {
            int f = (tile - 2) * 32 + m;
            const float* s = dcf + ((size_t)f * NTAP + t) * 4;
            cv[0] = 0.0f; cv[1] = s[0]; cv[2] = s[1];
            cv[3] = s[2]; cv[4] = s[3]; cv[5] = 0.0f;
        }
        unsigned short chi[6], clo[6];
#pragma unroll
        for (int e = 0; e < 6; ++e) {
            chi[e] = f2bf(cv[e]);
            clo[e] = f2bf(cv[e] - bf2f(chi[e]));
        }
        iv4 o;
        if (g == 0) {   // pairs with [phi0..phi5, plo1, plo2]
            o.x = pack2(chi[0], chi[1]); o.y = pack2(chi[2], chi[3]);
            o.z = pack2(chi[4], chi[5]); o.w = pack2(chi[1], chi[2]);
        } else {        // pairs with [plo3, plo4, plo5, phi1..phi5]
            o.x = pack2(chi[3], chi[4]); o.y = pack2(chi[5], clo[1]);
            o.z = pack2(clo[2], clo[3]); o.w = pack2(clo[4], clo[5]);
        }
        ac[idx] = o;
    }
}

// 1024 blocks x 512. Block = (b, h, w-half of 32 px). Wave v (0..7):
// f-half p = v&1, tap chunk q = v>>1 -> taps [72q, 72q+72).
__global__ __launch_bounds__(512, 4) void kan_mfma_kernel(
    const iv4* __restrict__ pw, const iv4* __restrict__ ac,
    float* __restrict__ out)
{
    const int tid = threadIdx.x;
    const int l = tid & 63, v = tid >> 6, ln = l & 31, g = l >> 5;
    const int p = v & 1, q = v >> 1;
    const int gb = (int)blockIdx.x;
    const int wh = gb & 1, h = (gb >> 1) & 63, bb = gb >> 7;
    const int w0 = wh << 5;

    __shared__ float red[4][2][64][16];   // exactly 32 KB, XOR-swizzled

    f16v acc, zf;
#pragma unroll
    for (int r = 0; r < 16; ++r) { acc[r] = 0.0f; zf[r] = 0.0f; }

    const iv4* __restrict__ pwg = pw + (size_t)g * NELEM;

    const int t0 = q * 72, tEnd = t0 + 72;

    // preload tap t0
    {
        // nothing
    }
    int k2 = t0 >> 5;
    int dy = k2 / 3, dx = k2 - dy * 3;
    int elem = ((bb * Cc + (t0 & 31)) * PW + (h + dy)) * PW + (w0 + ln + dx);
    const iv4* apl = ac + (size_t)t0 * 256 + p * 64 + l;
    iv4 blc = pwg[elem];
    iv4 Anc = apl[0], Adc = apl[128];

#pragma unroll 1
    for (int t = t0; t < tEnd; ++t) {
        // ---- prefetch tap t+1 (clamped; strength-reduced address) ----
        const int tn = t + 1;
        const int tl = (tn < tEnd) ? tn : t;      // wave-uniform
        int elemn;
        if (tl == t) {
            elemn = elem;                          // last iter: dup load
        } else if ((tl & 31) == 0) {
            // k2 boundary (wave-uniform, ~2x per chunk): full recompute
            const int k2n = tl >> 5;
            const int dyn = k2n / 3, dxn = k2n - dyn * 3;
            elemn = (bb * Cc * PW + (h + dyn)) * PW + (w0 + ln + dxn);
        } else {
            elemn = elem + PPLANE;                 // next channel, same window
        }
        const iv4* apn = apl + (size_t)(tl - t) * 256;
        iv4 bln = pwg[elemn];
        iv4 Ann = apn[0], Adn = apn[128];

        // ---- 2 MFMAs on current tap, D in VGPRs, explicit wait states ----
        f16v Dd, Dn;
        mfma2_v(__builtin_bit_cast(s8v, Adc), __builtin_bit_cast(s8v, Anc),
                __builtin_bit_cast(s8v, blc), zf, Dd, Dn);

        // ---- epilogue: 16 elems, add/rcp/fma ----
#pragma unroll
        for (int r = 0; r < 16; ++r) {
            float dd = 1.0f + __builtin_fabsf(Dd[r]);
            float rc = __builtin_amdgcn_rcpf(dd);
            acc[r] = __builtin_fmaf(Dn[r], rc, acc[r]);
        }

        elem = elemn; apl = apn;
        blc = bln; Anc = Ann; Adc = Adn;
    }

    // XOR swizzle: bank = 16*(l&1) + (r ^ ((l>>1)&15)) -> 2-way (free)
#pragma unroll
    for (int r = 0; r < 16; ++r)
        red[q][p][l][r ^ ((l >> 1) & 15)] = acc[r];
    __syncthreads();

    // combine 4 chunks; 512 threads x 4 outputs = 64f x 32px
    const int p2 = v & 1;
#pragma unroll
    for (int jj = 0; jj < 4; ++jj) {
        int r = (v >> 1) * 4 + jj;
        int rs = r ^ ((l >> 1) & 15);
        float s = red[0][p2][l][rs] + red[1][p2][l][rs]
                + red[2][p2][l][rs] + red[3][p2][l][rs];
        // C/D map (m74/m101): col = lane&31, row = (r&3)+8*(r>>2)+4*(lane>>5)
        int f = p2 * 32 + (r & 3) + ((r >> 2) << 3) + ((l >> 5) << 2);
        out[(((size_t)bb * Ff + f) * Hh + h) * Ww + w0 + ln] = s;
    }
}

extern "C" void kernel_launch(void* const* d_in, const int* in_sizes, int n_in,
                              void* d_out, int out_size, void* d_ws, size_t ws_size,
                              hipStream_t stream) {
    const float* x   = (const float*)d_in[0];
    const float* ncf = (const float*)d_in[1];
    const float* dcf = (const float*)d_in[2];
    float* out = (float*)d_out;

    iv4* pw = (iv4*)d_ws;            // 2 * 17.84 MB
    iv4* ac = pw + 2 * NELEM;        // 1.18 MB  (total ~36.9 MB)

    prep_kernel<<<PWBLK + NTAP, 256, 0, stream>>>(x, ncf, dcf, pw, ac);
    kan_mfma_kernel<<<1024, 512, 0, stream>>>(pw, ac, out);
}

// Round 9
// 163.904 us; speedup vs baseline: 1.0091x; 1.0091x over previous
//
#include <hip/hip_runtime.h>

// KAN-CNN via MFMA: out[b,f,h,w] = sum_{dy,dx,c} R_{f,dy,dx,c}( xpad[b,c,h+dy-1,w+dx-1] )
// R(x) = P5(x)/(1+|x*Q(x)|).
//
// R13 = R11 structure (8 waves/block, one f-half per wave, intrinsic MFMA)
// + paired-tap epilogue. Busy-cycle fit across R8-R12: v_rcp_f32 wave64
// occupies ~16 cyc -> 16 rcp/tap = ~75% of busy time; AGPR moves are
// second-order (R12 removed some, no net gain). R9 proved the pairing
// algebra but spilled (WRITE_SIZE 8192->11264, 8 live D tiles). Here:
// pair (t,t+1) in the 2-tile structure -> 4 live D tiles, live set ~122
// < 128 cap, no spill. Per elem-pair: n1/d1+n2/d2 = (n1*d2+n2*d1)*rcp(d1*d2)
// = 7 VALU + 1 rcp (vs 4 VALU + 2 rcp). Predicted busy 195k -> ~147k cyc.
// Ranges: d<=~600, d1*d2<=4e5, n*d<=3e6 -- f32-safe.
// No asm, no s_nops (R12's regression reverted).
//
// Precision unchanged from R8: hi/lo split on coeffs AND powers, K=16
// filled; C/D map m74/m101: row=(r&3)+8*(r>>2)+4*(lane>>5), col=lane&31.

typedef int   iv4  __attribute__((ext_vector_type(4)));
typedef short s8v  __attribute__((ext_vector_type(8)));
typedef float f16v __attribute__((ext_vector_type(16)));

#define Bb 8
#define Cc 32
#define Hh 64
#define Ww 64
#define Ff 64
#define PW 66
#define PPLANE (PW * PW)             // 4356
#define NELEM  (Bb * Cc * PPLANE)    // 1,115,136 elements
#define NTAP   288
#define PWBLK  (NELEM / 256)         // 4356 blocks for powers part

static __device__ __forceinline__ unsigned short f2bf(float f) {
    unsigned u = __builtin_bit_cast(unsigned, f);
    u += 0x7fffu + ((u >> 16) & 1u);           // RNE
    return (unsigned short)(u >> 16);
}
static __device__ __forceinline__ float bf2f(unsigned short h) {
    unsigned u = ((unsigned)h) << 16;
    return __builtin_bit_cast(float, u);
}
static __device__ __forceinline__ int pack2(unsigned short a, unsigned short b) {
    return (int)((unsigned)a | ((unsigned)b << 16));
}

// Merged prep: blocks [0, PWBLK) build the powers planes; blocks
// [PWBLK, PWBLK+288) build the A-coefficient fragments.
__global__ __launch_bounds__(256) void prep_kernel(
    const float* __restrict__ x,
    const float* __restrict__ ncf, const float* __restrict__ dcf,
    iv4* __restrict__ pw, iv4* __restrict__ ac)
{
    if ((int)blockIdx.x < PWBLK) {
        // ---- powers: two 16B rows per padded element, layout [g][elem] ----
        int idx = (int)blockIdx.x * 256 + (int)threadIdx.x;
        int wp = idx % PW;
        int r1 = idx / PW;
        int hp = r1 % PW;
        int pl = r1 / PW;                                 // b*32+c
        float v = 0.0f;
        if (hp >= 1 && hp <= Hh && wp >= 1 && wp <= Ww)
            v = x[((size_t)pl * Hh + (hp - 1)) * Ww + (wp - 1)];
        float p2 = v * v, p3 = p2 * v, p4 = p2 * p2, p5 = p4 * v;
        float pv[6] = {1.0f, v, p2, p3, p4, p5};
        unsigned short hi[6], lo[6];
#pragma unroll
        for (int e = 0; e < 6; ++e) {
            hi[e] = f2bf(pv[e]);
            lo[e] = f2bf(pv[e] - bf2f(hi[e]));
        }
        iv4 r0, r1v;
        r0.x  = pack2(hi[0], hi[1]); r0.y  = pack2(hi[2], hi[3]);
        r0.z  = pack2(hi[4], hi[5]); r0.w  = pack2(lo[1], lo[2]);
        r1v.x = pack2(lo[3], lo[4]); r1v.y = pack2(lo[5], hi[1]);
        r1v.z = pack2(hi[2], hi[3]); r1v.w = pack2(hi[4], hi[5]);
        pw[idx]         = r0;    // g=0 plane
        pw[NELEM + idx] = r1v;   // g=1 plane
    } else {
        // ---- A fragments: load-order [t(288)][Mtile(4)][lane(64)] x 16B ----
        // tiles: 0=num f0-31, 1=num f32-63, 2=den f0-31, 3=den f32-63
        int idx = ((int)blockIdx.x - PWBLK) * 256 + (int)threadIdx.x;
        int l = idx & 63, tile = (idx >> 6) & 3, t = idx >> 8;
        int m = l & 31, g = l >> 5;
        float cv[6];
        if (tile < 2) {
            int f = tile * 32 + m;
            const float* s = ncf + ((size_t)f * NTAP + t) * 6;
            cv[0] = s[0]; cv[1] = s[1]; cv[2] = s[2];
            cv[3] = s[3]; cv[4] = s[4]; cv[5] = s[5];
        } else {
            int f = (tile - 2) * 32 + m;
            const float* s = dcf + ((size_t)f * NTAP + t) * 4;
            cv[0] = 0.0f; cv[1] = s[0]; cv[2] = s[1];
            cv[3] = s[2]; cv[4] = s[3]; cv[5] = 0.0f;
        }
        unsigned short chi[6], clo[6];
#pragma unroll
        for (int e = 0; e < 6; ++e) {
            chi[e] = f2bf(cv[e]);
            clo[e] = f2bf(cv[e] - bf2f(chi[e]));
        }
        iv4 o;
        if (g == 0) {   // pairs with [phi0..phi5, plo1, plo2]
            o.x = pack2(chi[0], chi[1]); o.y = pack2(chi[2], chi[3]);
            o.z = pack2(chi[4], chi[5]); o.w = pack2(chi[1], chi[2]);
        } else {        // pairs with [plo3, plo4, plo5, phi1..phi5]
            o.x = pack2(chi[3], chi[4]); o.y = pack2(chi[5], clo[1]);
            o.z = pack2(clo[2], clo[3]); o.w = pack2(clo[4], clo[5]);
        }
        ac[idx] = o;
    }
}

// 1024 blocks x 512. Block = (b, h, w-half of 32 px). Wave v (0..7):
// f-half p = v&1, tap chunk q = v>>1 -> taps [72q, 72q+72) as 36 pairs.
__global__ __launch_bounds__(512, 4) void kan_mfma_kernel(
    const iv4* __restrict__ pw, const iv4* __restrict__ ac,
    float* __restrict__ out)
{
    const int tid = threadIdx.x;
    const int l = tid & 63, v = tid >> 6, ln = l & 31, g = l >> 5;
    const int p = v & 1, q = v >> 1;
    const int gb = (int)blockIdx.x;
    const int wh = gb & 1, h = (gb >> 1) & 63, bb = gb >> 7;
    const int w0 = wh << 5;

    __shared__ float red[4][2][64][16];   // exactly 32 KB, XOR-swizzled

    f16v acc, zf;
#pragma unroll
    for (int r = 0; r < 16; ++r) { acc[r] = 0.0f; zf[r] = 0.0f; }

    const iv4* __restrict__ pwg = pw + (size_t)g * NELEM;
    const int t0 = q * 72;

    // B address for pair start t0 (t0=72q: k2 = t0>>5, c = t0&31)
    {
    }
    int k20 = t0 >> 5;
    int dy0 = k20 / 3, dx0 = k20 - 3 * dy0;
    int elemBase = ((bb * Cc + (t0 & 31)) * PW + (h + dy0)) * PW + (w0 + ln + dx0);
    const iv4* apl = ac + (size_t)t0 * 256 + p * 64 + l;

#pragma unroll 1
    for (int j = 0; j < 36; ++j) {
        const int tp = t0 + 2 * j;                 // pair start (even)
        if (j > 0) {
            if ((tp & 31) == 0) {
                // k2 boundary (wave-uniform; pairs never straddle it)
                const int k2 = tp >> 5;
                const int dy = k2 / 3, dx = k2 - 3 * dy;
                elemBase = (bb * Cc * PW + (h + dy)) * PW + (w0 + ln + dx);
            } else {
                elemBase += 2 * PPLANE;            // next channel pair
            }
        }

        iv4 B0  = pwg[elemBase];
        iv4 B1  = pwg[elemBase + PPLANE];
        iv4 An0 = apl[0],   Ad0 = apl[128];
        iv4 An1 = apl[256], Ad1 = apl[384];
        apl += 512;

        s8v b0 = __builtin_bit_cast(s8v, B0);
        s8v b1 = __builtin_bit_cast(s8v, B1);

        f16v Dn0 = __builtin_amdgcn_mfma_f32_32x32x16_bf16(
            __builtin_bit_cast(s8v, An0), b0, zf, 0, 0, 0);
        f16v Dd0 = __builtin_amdgcn_mfma_f32_32x32x16_bf16(
            __builtin_bit_cast(s8v, Ad0), b0, zf, 0, 0, 0);
        f16v Dn1 = __builtin_amdgcn_mfma_f32_32x32x16_bf16(
            __builtin_bit_cast(s8v, An1), b1, zf, 0, 0, 0);
        f16v Dd1 = __builtin_amdgcn_mfma_f32_32x32x16_bf16(
            __builtin_bit_cast(s8v, Ad1), b1, zf, 0, 0, 0);

        // paired epilogue: ONE rcp per element-pair
#pragma unroll
        for (int r = 0; r < 16; ++r) {
            float da = 1.0f + __builtin_fabsf(Dd0[r]);
            float db = 1.0f + __builtin_fabsf(Dd1[r]);
            float nn = __builtin_fmaf(Dn0[r], db, Dn1[r] * da);
            float rc = __builtin_amdgcn_rcpf(da * db);
            acc[r] = __builtin_fmaf(nn, rc, acc[r]);
        }
    }

    // XOR swizzle: bank = 16*(l&1) + (r ^ ((l>>1)&15)) -> 2-way (free)
#pragma unroll
    for (int r = 0; r < 16; ++r)
        red[q][p][l][r ^ ((l >> 1) & 15)] = acc[r];
    __syncthreads();

    // combine 4 chunks; 512 threads x 4 outputs = 64f x 32px
    const int p2 = v & 1;
#pragma unroll
    for (int jj = 0; jj < 4; ++jj) {
        int r = (v >> 1) * 4 + jj;
        int rs = r ^ ((l >> 1) & 15);
        float s = red[0][p2][l][rs] + red[1][p2][l][rs]
                + red[2][p2][l][rs] + red[3][p2][l][rs];
        // C/D map (m74/m101): col = lane&31, row = (r&3)+8*(r>>2)+4*(lane>>5)
        int f = p2 * 32 + (r & 3) + ((r >> 2) << 3) + ((l >> 5) << 2);
        out[(((size_t)bb * Ff + f) * Hh + h) * Ww + w0 + ln] = s;
    }
}

extern "C" void kernel_launch(void* const* d_in, const int* in_sizes, int n_in,
                              void* d_out, int out_size, void* d_ws, size_t ws_size,
                              hipStream_t stream) {
    const float* x   = (const float*)d_in[0];
    const float* ncf = (const float*)d_in[1];
    const float* dcf = (const float*)d_in[2];
    float* out = (float*)d_out;

    iv4* pw = (iv4*)d_ws;            // 2 * 17.84 MB
    iv4* ac = pw + 2 * NELEM;        // 1.18 MB  (total ~36.9 MB)

    prep_kernel<<<PWBLK + NTAP, 256, 0, stream>>>(x, ncf, dcf, pw, ac);
    kan_mfma_kernel<<<1024, 512, 0, stream>>>(pw, ac, out);
}